// Round 6
// baseline (140.797 us; speedup 1.0000x reference)
//
#include <hip/hip_runtime.h>
#include <math.h>

// DenseCaps dynamic routing, MI355X. B=32, I=4096, O=32, 4x4 poses, 3 iters.
// R5 post-mortem: pass kernels are VALU-ISSUE-bound on fp32 fma (~106
// instr/lane/i, 22.6 us/pass issue floor, measured ~25). This round halves
// the fma count with v_dot2_f32_f16 (2 MACs/instr, fp32 accumulate): one-time
// pack kernel converts poses/w to f16 pre-paired along y (4 MB each in ws).
// Votes 64 fma -> 32 fdot2; w LDS row 64->32 B (2x ds_read_b128). d-dot,
// s-accumulation, softmax remain fp32. Deterministic partial stores + reduce
// kernel as before. No atomics on the main path, no cooperative launch.

#define NB 32
#define NI 4096
#define NO 32
#define I_TILE 16
#define NCHUNK (NI / I_TILE)        // 256
#define B_TILE 8
#define NBG (NB / B_TILE)           // 4
#define SOFF (NB * NO * 16)         // 16384 floats per (chunk) partial slab
#define EPSF 1e-12f

typedef _Float16 v2h __attribute__((ext_vector_type(2)));

#if __has_builtin(__builtin_amdgcn_fdot2)
__device__ __forceinline__ float fdot2(v2h a, v2h b, float c) {
    return __builtin_amdgcn_fdot2(a, b, c, false);
}
#else
__device__ __forceinline__ float fdot2(v2h a, v2h b, float c) {
    return fmaf((float)a.x, (float)b.x, fmaf((float)a.y, (float)b.y, c));
}
#endif

__device__ __forceinline__ float dot4(const float4 a, const float4 b) {
    return fmaf(a.x, b.x, fmaf(a.y, b.y, fmaf(a.z, b.z, a.w * b.w)));
}

__device__ __forceinline__ void fma4(float4& s, const float c, const float4 t) {
    s.x = fmaf(c, t.x, s.x);
    s.y = fmaf(c, t.y, s.y);
    s.z = fmaf(c, t.z, s.z);
    s.w = fmaf(c, t.w, s.w);
}

// x + dpp_perm(x); ctrl: 0xB1=quad_perm xor1, 0x4E=quad_perm xor2,
// 0x141=row_half_mirror (xor7), 0x140=row_mirror (xor15).
template <int CTRL>
__device__ __forceinline__ float dpp_add(float x) {
    int xi = __builtin_bit_cast(int, x);
    int yi = __builtin_amdgcn_update_dpp(0, xi, CTRL, 0xf, 0xf, false);
    return x + __builtin_bit_cast(float, yi);
}

// sum over each 32-lane half (the o-group)
__device__ __forceinline__ float sum32(float x) {
    x = dpp_add<0xB1>(x);    // xor1
    x = dpp_add<0x4E>(x);    // xor2
    x = dpp_add<0x141>(x);   // xor7 -> with above spans xor4
    x = dpp_add<0x140>(x);   // xor15 -> spans xor8 (row of 16 done)
    int t = __builtin_amdgcn_ds_swizzle(__builtin_bit_cast(int, x), 0x401F);
    return x + __builtin_bit_cast(float, t);   // xor16 within 32-lane group
}

// ---------------- one-time f16 pack kernel ----------------
// n in [0, 131072): packs w element (o,i)=n AND poses element (b,i)=n.
// wp[n]: 8 v2h, z-major: (W[0][z],W[1][z]),(W[2][z],W[3][z]) for z=0..3
// pp[n]: 8 v2h, x-major: (P[x][0],P[x][1]),(P[x][2],P[x][3]) for x=0..3
__global__ __launch_bounds__(256) void caps_pack(
    const float* __restrict__ poses, const float* __restrict__ w,
    v2h* __restrict__ pp, v2h* __restrict__ wp)
{
    const int n = blockIdx.x * 256 + threadIdx.x;
    if (n >= NO * NI) return;
    {
        float Wv[16];   // [y][z]
        const float4* src = (const float4*)(w + ((size_t)n << 4));
        *(float4*)&Wv[0] = src[0]; *(float4*)&Wv[4]  = src[1];
        *(float4*)&Wv[8] = src[2]; *(float4*)&Wv[12] = src[3];
        v2h o8[8];
        #pragma unroll
        for (int z = 0; z < 4; ++z) {
            v2h a, b;
            a.x = (_Float16)Wv[0 * 4 + z]; a.y = (_Float16)Wv[1 * 4 + z];
            b.x = (_Float16)Wv[2 * 4 + z]; b.y = (_Float16)Wv[3 * 4 + z];
            o8[2 * z] = a; o8[2 * z + 1] = b;
        }
        uint4* dst = (uint4*)(wp + (size_t)n * 8);
        dst[0] = *(uint4*)&o8[0];
        dst[1] = *(uint4*)&o8[4];
    }
    {
        float Pv[16];   // [x][y]
        const float4* src = (const float4*)(poses + ((size_t)n << 4));
        *(float4*)&Pv[0] = src[0]; *(float4*)&Pv[4]  = src[1];
        *(float4*)&Pv[8] = src[2]; *(float4*)&Pv[12] = src[3];
        v2h o8[8];
        #pragma unroll
        for (int x = 0; x < 4; ++x) {
            v2h a, b;
            a.x = (_Float16)Pv[x * 4 + 0]; a.y = (_Float16)Pv[x * 4 + 1];
            b.x = (_Float16)Pv[x * 4 + 2]; b.y = (_Float16)Pv[x * 4 + 3];
            o8[2 * x] = a; o8[2 * x + 1] = b;
        }
        uint4* dst = (uint4*)(pp + (size_t)n * 8);
        dst[0] = *(uint4*)&o8[0];
        dst[1] = *(uint4*)&o8[4];
    }
}

// ---------------- pass kernel (f16 dot2 votes) ----------------
__global__ __launch_bounds__(256, 4) void caps_pass_st(
    const v2h* __restrict__ pp, const v2h* __restrict__ wp,
    const float* __restrict__ v_buf, float* __restrict__ s_part,
    const int pass)
{
    __shared__ uint4 wsm[I_TILE][32][2];   // 16 KB
    const int tid    = threadIdx.x;
    const int chunk  = blockIdx.x;
    const int bgroup = blockIdx.y;
    const int ibase  = chunk * I_TILE;

    // stage packed w tile, fully coalesced (16 B granules, o-major source)
    const uint4* wpu = (const uint4*)wp;
    #pragma unroll
    for (int r = 0; r < 4; ++r) {
        const int idx = r * 256 + tid;     // 0..1023
        const int o_l = idx >> 5;
        const int rem = idx & 31;
        const int i_l = rem >> 1;
        const int h   = rem & 1;
        wsm[i_l][o_l][h] = wpu[((size_t)(o_l * NI + ibase + i_l) << 1) + h];
    }

    const int o    = tid & 31;
    const int bsub = tid >> 5;
    const int b    = bgroup * B_TILE + bsub;
    const int bo   = b * NO + o;

    float4 vv0 = {0,0,0,0}, vv1 = {0,0,0,0}, vv2 = {0,0,0,0}, vv3 = {0,0,0,0};
    if (pass > 0) {
        const float4* vp = (const float4*)(v_buf + (bo << 4));
        vv0 = vp[0]; vv1 = vp[1]; vv2 = vp[2]; vv3 = vp[3];
    }

    const uint4* ppu = (const uint4*)(pp + ((size_t)(b * NI + ibase) << 3));

    __syncthreads();

    float4 s0 = {0,0,0,0}, s1 = {0,0,0,0}, s2 = {0,0,0,0}, s3 = {0,0,0,0};

    #pragma unroll 2
    for (int i = 0; i < I_TILE; ++i) {
        const uint4 pa = ppu[2 * i + 0];   // x0,x1 (each: y01,y23 pairs)
        const uint4 pb = ppu[2 * i + 1];   // x2,x3
        const uint4 wa = wsm[i][o][0];     // z0,z1
        const uint4 wb = wsm[i][o][1];     // z2,z3
        const v2h* ph0 = (const v2h*)&pa;  // [0]=x0y01 [1]=x0y23 [2]=x1y01 [3]=x1y23
        const v2h* ph1 = (const v2h*)&pb;
        const v2h* wh0 = (const v2h*)&wa;  // [0]=z0y01 [1]=z0y23 [2]=z1y01 [3]=z1y23
        const v2h* wh1 = (const v2h*)&wb;

        float4 t0, t1, t2, t3;
        // votes[x][z] = sum_y P[x,y] W[y,z] via 2 chained fdot2
        t0.x = fdot2(ph0[0], wh0[0], fdot2(ph0[1], wh0[1], 0.0f));
        t0.y = fdot2(ph0[0], wh0[2], fdot2(ph0[1], wh0[3], 0.0f));
        t0.z = fdot2(ph0[0], wh1[0], fdot2(ph0[1], wh1[1], 0.0f));
        t0.w = fdot2(ph0[0], wh1[2], fdot2(ph0[1], wh1[3], 0.0f));
        t1.x = fdot2(ph0[2], wh0[0], fdot2(ph0[3], wh0[1], 0.0f));
        t1.y = fdot2(ph0[2], wh0[2], fdot2(ph0[3], wh0[3], 0.0f));
        t1.z = fdot2(ph0[2], wh1[0], fdot2(ph0[3], wh1[1], 0.0f));
        t1.w = fdot2(ph0[2], wh1[2], fdot2(ph0[3], wh1[3], 0.0f));
        t2.x = fdot2(ph1[0], wh0[0], fdot2(ph1[1], wh0[1], 0.0f));
        t2.y = fdot2(ph1[0], wh0[2], fdot2(ph1[1], wh0[3], 0.0f));
        t2.z = fdot2(ph1[0], wh1[0], fdot2(ph1[1], wh1[1], 0.0f));
        t2.w = fdot2(ph1[0], wh1[2], fdot2(ph1[1], wh1[3], 0.0f));
        t3.x = fdot2(ph1[2], wh0[0], fdot2(ph1[3], wh0[1], 0.0f));
        t3.y = fdot2(ph1[2], wh0[2], fdot2(ph1[3], wh0[3], 0.0f));
        t3.z = fdot2(ph1[2], wh1[0], fdot2(ph1[3], wh1[1], 0.0f));
        t3.w = fdot2(ph1[2], wh1[2], fdot2(ph1[3], wh1[3], 0.0f));

        float cc;
        if (pass == 0) {
            cc = 1.0f / 32.0f;
        } else {
            // softmax over o without max-shift: |d| bounded (~<4), exp safe.
            const float d = dot4(t0,vv0) + dot4(t1,vv1)
                          + dot4(t2,vv2) + dot4(t3,vv3);
            const float e  = __expf(d);
            const float es = sum32(e);
            cc = __fdividef(e, es);
        }
        fma4(s0, cc, t0); fma4(s1, cc, t1);
        fma4(s2, cc, t2); fma4(s3, cc, t3);
    }

    // deterministic partial store: [chunk][bo][16], fully coalesced
    float4* sp = (float4*)(s_part + ((size_t)chunk * (NB * NO) + bo) * 16);
    sp[0] = s0; sp[1] = s1; sp[2] = s2; sp[3] = s3;
}

// ---------------- reduce + squash kernel ----------------
__global__ __launch_bounds__(256) void caps_reduce(
    const float* __restrict__ s_part, float* __restrict__ v_buf,
    float* __restrict__ out, const int pass)
{
    const int e  = threadIdx.x & 63;
    const int c4 = threadIdx.x >> 6;
    const int eg = blockIdx.x * 64 + e;   // global element: bo*16 + k

    float acc = 0.0f;
    #pragma unroll 8
    for (int j = 0; j < NCHUNK / 4; ++j) {
        const int c = c4 * (NCHUNK / 4) + j;
        acc += s_part[(size_t)c * SOFF + eg];
    }
    __shared__ float red[4][64];
    red[c4][e] = acc;
    __syncthreads();

    if (threadIdx.x < 64) {
        const float a = red[0][e] + red[1][e] + red[2][e] + red[3][e];
        float x = a * a;
        #pragma unroll
        for (int msk = 8; msk >= 1; msk >>= 1)
            x += __shfl_xor(x, msk, 16);
        const float n2 = x;
        const float n  = sqrtf(n2 + EPSF);
        const float sc = (n2 / (1.0f + n2)) / n;
        if (pass < 2) {
            const float vold = (pass == 0) ? 0.0f : v_buf[eg];
            v_buf[eg] = fmaf(sc, a, vold);
        } else {
            out[eg] = sc * a;
            if ((e & 15) == 0)
                out[NB * NO * 16 + (eg >> 4)] = sqrtf(n2 * sc * sc + EPSF);
        }
    }
}

// ---------------- fallback: proven fp32 kernels (small ws) ----------------
#define FB_CHUNKS 32
#define FB_IPB (NI / FB_CHUNKS)

__device__ __forceinline__ float4 row_mm(const float4 p, const float4 w0,
                                         const float4 w1, const float4 w2,
                                         const float4 w3) {
    float4 r;
    r.x = fmaf(p.x, w0.x, fmaf(p.y, w1.x, fmaf(p.z, w2.x, p.w * w3.x)));
    r.y = fmaf(p.x, w0.y, fmaf(p.y, w1.y, fmaf(p.z, w2.y, p.w * w3.y)));
    r.z = fmaf(p.x, w0.z, fmaf(p.y, w1.z, fmaf(p.z, w2.z, p.w * w3.z)));
    r.w = fmaf(p.x, w0.w, fmaf(p.y, w1.w, fmaf(p.z, w2.w, p.w * w3.w)));
    return r;
}

__global__ __launch_bounds__(256) void caps_pass_fb(
    const float* __restrict__ poses, const float* __restrict__ w,
    const float* __restrict__ v_buf, float* __restrict__ s_buf, const int mode)
{
    const int tid   = threadIdx.x;
    const int b     = blockIdx.y;
    const int chunk = blockIdx.x;
    const int o     = tid & 31;
    const int g     = tid >> 5;

    float4 v0 = {0,0,0,0}, v1 = {0,0,0,0}, v2 = {0,0,0,0}, v3 = {0,0,0,0};
    if (mode != 0) {
        const float4* vp = (const float4*)(v_buf + (((b * NO) + o) << 4));
        v0 = vp[0]; v1 = vp[1]; v2 = vp[2]; v3 = vp[3];
    }
    float4 s0 = {0,0,0,0}, s1 = {0,0,0,0}, s2 = {0,0,0,0}, s3 = {0,0,0,0};
    const int ibase = chunk * FB_IPB + g;
    #pragma unroll 4
    for (int it = 0; it < FB_IPB / 8; ++it) {
        const int i = ibase + (it << 3);
        const float4* ppf = (const float4*)(poses + ((((size_t)b * NI) + i) << 4));
        const float4 p0 = ppf[0], p1 = ppf[1], p2 = ppf[2], p3 = ppf[3];
        const float4* wpf = (const float4*)(w + ((((size_t)o * NI) + i) << 4));
        const float4 w0 = wpf[0], w1 = wpf[1], w2 = wpf[2], w3 = wpf[3];
        const float4 t0 = row_mm(p0, w0, w1, w2, w3);
        const float4 t1 = row_mm(p1, w0, w1, w2, w3);
        const float4 t2 = row_mm(p2, w0, w1, w2, w3);
        const float4 t3 = row_mm(p3, w0, w1, w2, w3);
        float cc;
        if (mode == 0) {
            cc = 1.0f / 32.0f;
        } else {
            float d = dot4(t0,v0) + dot4(t1,v1) + dot4(t2,v2) + dot4(t3,v3);
            const float e  = __expf(d);
            const float es = sum32(e);
            cc = __fdividef(e, es);
        }
        fma4(s0, cc, t0); fma4(s1, cc, t1);
        fma4(s2, cc, t2); fma4(s3, cc, t3);
    }
    __shared__ float red[8][32][16];
    float4* rp = (float4*)&red[g][o][0];
    rp[0] = s0; rp[1] = s1; rp[2] = s2; rp[3] = s3;
    __syncthreads();
    for (int idx = tid; idx < NO * 16; idx += 256) {
        const int oo = idx >> 4;
        const int k  = idx & 15;
        float acc = red[0][oo][k];
        #pragma unroll
        for (int gg = 1; gg < 8; ++gg) acc += red[gg][oo][k];
        atomicAdd(&s_buf[(((b * NO) + oo) << 4) + k], acc);
    }
}

__global__ __launch_bounds__(256) void caps_squash_fb(
    float* __restrict__ s_buf, float* __restrict__ v_buf,
    float* __restrict__ out, const int mode)
{
    const int idx = blockIdx.x * 256 + threadIdx.x;
    if (idx >= NB * NO) return;
    float4* sp = (float4*)(s_buf + (idx << 4));
    const float4 s0 = sp[0], s1 = sp[1], s2 = sp[2], s3 = sp[3];
    const float n2 = dot4(s0,s0) + dot4(s1,s1) + dot4(s2,s2) + dot4(s3,s3);
    const float n  = sqrtf(n2 + EPSF);
    const float sc = (n2 / (1.0f + n2)) / n;
    if (mode == 2) {
        float4* op = (float4*)(out + (idx << 4));
        op[0] = make_float4(sc*s0.x, sc*s0.y, sc*s0.z, sc*s0.w);
        op[1] = make_float4(sc*s1.x, sc*s1.y, sc*s1.z, sc*s1.w);
        op[2] = make_float4(sc*s2.x, sc*s2.y, sc*s2.z, sc*s2.w);
        op[3] = make_float4(sc*s3.x, sc*s3.y, sc*s3.z, sc*s3.w);
        out[NB * NO * 16 + idx] = sqrtf(n2 * sc * sc + EPSF);
    } else {
        float4* vp = (float4*)(v_buf + (idx << 4));
        float4 a0 = {0,0,0,0}, a1 = {0,0,0,0}, a2 = {0,0,0,0}, a3 = {0,0,0,0};
        if (mode != 0) { a0 = vp[0]; a1 = vp[1]; a2 = vp[2]; a3 = vp[3]; }
        vp[0] = make_float4(fmaf(sc,s0.x,a0.x), fmaf(sc,s0.y,a0.y), fmaf(sc,s0.z,a0.z), fmaf(sc,s0.w,a0.w));
        vp[1] = make_float4(fmaf(sc,s1.x,a1.x), fmaf(sc,s1.y,a1.y), fmaf(sc,s1.z,a1.z), fmaf(sc,s1.w,a1.w));
        vp[2] = make_float4(fmaf(sc,s2.x,a2.x), fmaf(sc,s2.y,a2.y), fmaf(sc,s2.z,a2.z), fmaf(sc,s2.w,a2.w));
        vp[3] = make_float4(fmaf(sc,s3.x,a3.x), fmaf(sc,s3.y,a3.y), fmaf(sc,s3.z,a3.z), fmaf(sc,s3.w,a3.w));
        const float4 z = {0,0,0,0};
        sp[0] = z; sp[1] = z; sp[2] = z; sp[3] = z;
    }
}

extern "C" void kernel_launch(void* const* d_in, const int* in_sizes, int n_in,
                              void* d_out, int out_size, void* d_ws, size_t ws_size,
                              hipStream_t stream) {
    const float* poses = (const float*)d_in[0];   // [B, I, 4, 4]
    // d_in[1] = input_activations — unused by the reference computation
    const float* w     = (const float*)d_in[2];   // [O, I, 4, 4]
    float* out = (float*)d_out;                   // [B,O,16] poses ++ [B,O] acts

    // ws: s_part 16.8MB + v 64KB + pp 4MB + wp 4MB  (~25.2 MB)
    const size_t need = ((size_t)NCHUNK * SOFF + SOFF) * sizeof(float)
                      + (size_t)2 * NO * NI * 8 * sizeof(v2h);
    if (ws_size >= need) {
        float* s_part = (float*)d_ws;             // [NCHUNK][B*O][16]
        float* v_buf  = s_part + (size_t)NCHUNK * SOFF;
        v2h*   pp     = (v2h*)(v_buf + SOFF);     // [B*I][8]
        v2h*   wp     = pp + (size_t)NO * NI * 8; // [O*I][8]

        caps_pack<<<(NO * NI + 255) / 256, 256, 0, stream>>>(poses, w, pp, wp);

        dim3 gp(NCHUNK, NBG), blk(256), gr(256);
        for (int pass = 0; pass < 3; ++pass) {
            caps_pass_st<<<gp, blk, 0, stream>>>(pp, wp, v_buf, s_part, pass);
            caps_reduce<<<gr, blk, 0, stream>>>(s_part, v_buf, out, pass);
        }
    } else {
        // proven fp32 path (small workspace)
        float* s_buf = (float*)d_ws;
        float* v_buf = s_buf + SOFF;
        hipMemsetAsync(s_buf, 0, SOFF * sizeof(float), stream);
        dim3 grid(FB_CHUNKS, NB), block(256);
        for (int pass = 0; pass < 3; ++pass) {
            caps_pass_fb<<<grid, block, 0, stream>>>(poses, w, v_buf, s_buf, pass);
            caps_squash_fb<<<4, 256, 0, stream>>>(s_buf, v_buf, out, pass);
        }
    }
}